// Round 5
// baseline (399.730 us; speedup 1.0000x reference)
//
#include <hip/hip_runtime.h>
#include <cstdint>
#include <cstddef>

// ---------------------------------------------------------------------------
// NaiveSDPA: out[n,s,v] = softmax(Q·K^T / 8 + mask) · V ; f32 I/O, bf16 MFMA.
// v5: S^T = K·Q^T (in-thread softmax sums; P^T C-layout == x16 B-frag).
// K and V^T pre-packed bf16 in LDS. Bank-exact strides (K 144B rows, Vt 136B
// rows); stageV thread mapping fixed so every 16-lane phase hits 16 distinct
// bank-pairs (was 4-way conflicted). 4 blocks/CU (all 1024 blocks resident).
// v_cvt_pk_bf16_f32 when available. BK=64, double-buffered, 1 barrier/iter.
// ---------------------------------------------------------------------------

typedef __attribute__((ext_vector_type(8))) short short8;
typedef __attribute__((ext_vector_type(4))) short short4v;
typedef __attribute__((ext_vector_type(4))) float f32x4;
typedef __attribute__((ext_vector_type(4))) unsigned int uint4v;
typedef __attribute__((ext_vector_type(2))) unsigned int uint2v;

#define DEV __device__ __forceinline__

constexpr int N_B   = 16;
constexpr int S_Q   = 4096;
constexpr int S_KV  = 4096;
constexpr int DH    = 64;
constexpr int BQ    = 64;
constexpr int BK    = 64;
constexpr int ITERS = S_KV / BK;   // 64
constexpr int KSTR  = 72;          // shorts/row: 144B (skew 4 dwords)
constexpr int VSTR  = 68;          // shorts/row: 136B (skew 2 dwords)

#define LOG2E 1.44269504088896340736f

DEV unsigned short f2bf(float f) {           // RNE f32 -> bf16
  union { float f; unsigned int i; } x; x.f = f;
  unsigned int r = x.i + 0x7FFFu + ((x.i >> 16) & 1u);
  return (unsigned short)(r >> 16);
}

#if __has_builtin(__builtin_amdgcn_cvt_pk_bf16_f32)
typedef __attribute__((ext_vector_type(2))) __bf16 bf16x2v;
DEV unsigned int packrne(float a, float b) {   // bf16(a) lo | bf16(b) hi, RNE
  union { bf16x2v v; unsigned int u; } x;
  x.v = __builtin_amdgcn_cvt_pk_bf16_f32(a, b);
  return x.u;
}
DEV unsigned int packst(float a, float b) { return packrne(a, b); }
#else
DEV unsigned int packrne(float a, float b) {   // manual RNE pack
  union { float f; unsigned int u; } ua, ub; ua.f = a; ub.f = b;
  unsigned int ra = ua.u + 0x7FFFu + ((ua.u >> 16) & 1u);
  unsigned int rb = ub.u + 0x7FFFu + ((ub.u >> 16) & 1u);
  return __builtin_amdgcn_perm(rb, ra, 0x07060302u);
}
DEV unsigned int packst(float a, float b) {    // truncating pack (staging)
  union { float f; unsigned int u; } ua, ub; ua.f = a; ub.f = b;
  return __builtin_amdgcn_perm(ub.u, ua.u, 0x07060302u);
}
#endif

DEV f32x4 mfma16(short4v a, short4v b, f32x4 c) {
#if __has_builtin(__builtin_amdgcn_mfma_f32_16x16x16bf16_1k)
  return __builtin_amdgcn_mfma_f32_16x16x16bf16_1k(a, b, c, 0, 0, 0);
#elif __has_builtin(__builtin_amdgcn_mfma_f32_16x16x16_bf16)
  return __builtin_amdgcn_mfma_f32_16x16x16_bf16(a, b, c, 0, 0, 0);
#else
  asm volatile("v_mfma_f32_16x16x16_bf16 %0, %1, %2, %0\n\ts_nop 7\n\ts_nop 7"
               : "+v"(c) : "v"(a), "v"(b));
  return c;
#endif
}

// stage K tile: thread t owns 16B chunks (r=t>>3, c=t&7) and (r+32, c).
// Phase-clean: lanes 0..7 have distinct c -> distinct 4-bank groups.
DEV void stageK(unsigned short* buf, const f32x4* kA, int t) {
  const int r0 = t >> 3, c = t & 7;
  uint4v d0, d1;
  d0[0] = packst(kA[0][0], kA[0][1]); d0[1] = packst(kA[0][2], kA[0][3]);
  d0[2] = packst(kA[1][0], kA[1][1]); d0[3] = packst(kA[1][2], kA[1][3]);
  d1[0] = packst(kA[2][0], kA[2][1]); d1[1] = packst(kA[2][2], kA[2][3]);
  d1[2] = packst(kA[3][0], kA[3][1]); d1[3] = packst(kA[3][2], kA[3][3]);
  *(uint4v*)&buf[r0 * KSTR + c * 8]        = d0;
  *(uint4v*)&buf[(r0 + 32) * KSTR + c * 8] = d1;
}

// stage V^T tile: thread t loaded L[i] = V[kv=4*(t&15)+i][4*(t>>4)..+3];
// transpose 4x4 in regs, write 4 x b64. Within a 16-lane phase t>>4 is
// constant and a=t&15 varies -> banks 2*((v0+j+a)&15): 16 distinct pairs.
DEV void stageV(unsigned short* buf, const f32x4* L, int t) {
  const int a  = t & 15;          // kv/4 index
  const int v0 = (t >> 4) * 4;    // vcol base
#pragma unroll
  for (int j = 0; j < 4; ++j) {
    uint2v d;
    d[0] = packst(L[0][j], L[1][j]);
    d[1] = packst(L[2][j], L[3][j]);
    *(uint2v*)&buf[(v0 + j) * VSTR + a * 4] = d;
  }
}

__global__ __launch_bounds__(256, 4)
void sdpa_fwd(const float* __restrict__ Qg,
              const float* __restrict__ Kg,
              const float* __restrict__ Vg,
              const float* __restrict__ Mg,
              float* __restrict__ Og)
{
  __shared__ __align__(16) unsigned short ldsK[2][BK * KSTR];  // 2 x 9216 B
  __shared__ __align__(16) unsigned short ldsV[2][DH * VSTR];  // 2 x 8704 B

  const int n    = blockIdx.y;
  const int q0   = blockIdx.x * BQ;
  const int t    = threadIdx.x;
  const int w    = t >> 6;
  const int lane = t & 63;
  const int l15  = lane & 15;
  const int quad = lane >> 4;

  // ---- Q B-frags (RNE once): Q[q=l15][d=quad*8+j] (+32 for qf1)
  short8 qf0, qf1;
  {
    const float* qp =
        Qg + ((size_t)n * S_Q + (size_t)(q0 + w * 16 + l15)) * DH + quad * 8;
#pragma unroll
    for (int j = 0; j < 8; ++j) {
      qf0[j] = (short)f2bf(qp[j]);
      qf1[j] = (short)f2bf(qp[32 + j]);
    }
  }

  // ---- staging source pointers
  const float* kgp = Kg + ((size_t)n * S_KV + (t >> 3)) * DH + (t & 7) * 8;
  const float* vgp =
      Vg + ((size_t)n * S_KV + (size_t)(t & 15) * 4) * DH + (t >> 4) * 4;
  const float* mrow = Mg + (size_t)(q0 + w * 16 + l15) * S_KV + quad * 4;

  // ---- O^T accumulators (C-layout: row v=16nt+quad*4+r, col q=l15)
  f32x4 acc[4];
#pragma unroll
  for (int nt = 0; nt < 4; ++nt)
#pragma unroll
    for (int r = 0; r < 4; ++r) acc[nt][r] = 0.0f;
  float lrun = 0.0f;

  // ---- prologue: load + stage tile 0
  f32x4 kA[4], vL[4];
  kA[0] = *(const f32x4*)(kgp);
  kA[1] = *(const f32x4*)(kgp + 4);
  kA[2] = *(const f32x4*)(kgp + 32 * DH);
  kA[3] = *(const f32x4*)(kgp + 32 * DH + 4);
#pragma unroll
  for (int i = 0; i < 4; ++i) vL[i] = *(const f32x4*)(vgp + i * DH);
  stageK(&ldsK[0][0], kA, t);
  stageV(&ldsV[0][0], vL, t);
  __syncthreads();

  for (int it = 0; it < ITERS; ++it) {
    const int p   = it & 1;
    const int kv0 = it * BK;
    const bool more = (it + 1 < ITERS);

    // prefetch next tile into regs (latency hidden by the body)
    if (more) {
      const float* kn = kgp + (size_t)(kv0 + BK) * DH;
      kA[0] = *(const f32x4*)(kn);
      kA[1] = *(const f32x4*)(kn + 4);
      kA[2] = *(const f32x4*)(kn + 32 * DH);
      kA[3] = *(const f32x4*)(kn + 32 * DH + 4);
      const float* vn = vgp + (size_t)(kv0 + BK) * DH;
#pragma unroll
      for (int i = 0; i < 4; ++i) vL[i] = *(const f32x4*)(vn + i * DH);
    }

    // mask: 4 x float4, kv = kv0+16h+quad*4..+3, row q=l15
    f32x4 mk[4];
#pragma unroll
    for (int h = 0; h < 4; ++h)
      mk[h] = *(const f32x4*)(mrow + kv0 + 16 * h);

    // K A-frags: direct b128 bf16 reads, A[m=kv=l15+16h][k=d=quad*8+j+32kk]
    short8 kf[4][2];
#pragma unroll
    for (int h = 0; h < 4; ++h)
#pragma unroll
      for (int kk = 0; kk < 2; ++kk)
        kf[h][kk] =
            *(const short8*)&ldsK[p][(l15 + 16 * h) * KSTR + (quad + 4 * kk) * 8];

    // S^T = K·Q^T ; p = exp2((s/8 + m)·log2e), no max subtraction
    float pvv[4][4];
    float rs = 0.0f;
#pragma unroll
    for (int h = 0; h < 4; ++h) {
      f32x4 c = {0.f, 0.f, 0.f, 0.f};
      c = __builtin_amdgcn_mfma_f32_16x16x32_bf16(kf[h][0], qf0, c, 0, 0, 0);
      c = __builtin_amdgcn_mfma_f32_16x16x32_bf16(kf[h][1], qf1, c, 0, 0, 0);
#pragma unroll
      for (int r = 0; r < 4; ++r) {
        float e = __builtin_amdgcn_exp2f(fmaf(c[r], 0.125f, mk[h][r]) * LOG2E);
        pvv[h][r] = e;
        rs += e;
      }
    }
    rs += __shfl_xor(rs, 16, 64);
    rs += __shfl_xor(rs, 32, 64);
    lrun += rs;

    // P^T frags for x16 (k=kv=quad*4+j, n=q=l15) — already in-thread
    short4v pf[4];
#pragma unroll
    for (int h = 0; h < 4; ++h) {
      union { uint2v u; short4v s; } uu;
      uu.u[0] = packrne(pvv[h][0], pvv[h][1]);
      uu.u[1] = packrne(pvv[h][2], pvv[h][3]);
      pf[h] = uu.s;
    }

    // PV: O^T += V^T·P^T ; A-frag b64: V^T[vcol=l15+16nt][kv=16h+4quad+j]
#pragma unroll
    for (int nt = 0; nt < 4; ++nt)
#pragma unroll
      for (int h = 0; h < 4; ++h) {
        short4v vf =
            *(const short4v*)&ldsV[p][(l15 + 16 * nt) * VSTR + (4 * h + quad) * 4];
        acc[nt] = mfma16(vf, pf[h], acc[nt]);
      }

    // stage prefetched tile into the other buffer
    if (more) {
      stageK(&ldsK[p ^ 1][0], kA, t);
      stageV(&ldsV[p ^ 1][0], vL, t);
    }
    __syncthreads();
  }

  // ---- epilogue: O[q][v] = O^T[v][q] / l ; coalesced f32x4 stores
  const float inv = 1.0f / lrun;
  float* ob = Og + ((size_t)n * S_Q + (size_t)(q0 + w * 16 + l15)) * DH
            + quad * 4;
#pragma unroll
  for (int nt = 0; nt < 4; ++nt) {
    f32x4 o;
#pragma unroll
    for (int r = 0; r < 4; ++r) o[r] = acc[nt][r] * inv;
    *(f32x4*)(ob + 16 * nt) = o;
  }
}

extern "C" void kernel_launch(void* const* d_in, const int* in_sizes, int n_in,
                              void* d_out, int out_size, void* d_ws, size_t ws_size,
                              hipStream_t stream) {
  (void)in_sizes; (void)n_in; (void)d_ws; (void)ws_size; (void)out_size;
  const float* q = (const float*)d_in[0];
  const float* k = (const float*)d_in[1];
  const float* v = (const float*)d_in[2];
  const float* m = (const float*)d_in[3];
  float* o = (float*)d_out;

  dim3 grid(S_Q / BQ, N_B);   // (64, 16) — flat%8 groups same q0%8 per XCD
  dim3 block(256);
  hipLaunchKernelGGL(sdpa_fwd, grid, block, 0, stream, q, k, v, m, o);
}

// Round 6
// 308.945 us; speedup vs baseline: 1.2939x; 1.2939x over previous
//
#include <hip/hip_runtime.h>
#include <cstdint>
#include <cstddef>

// ---------------------------------------------------------------------------
// NaiveSDPA: out[n,s,v] = softmax(Q·K^T / 8 + mask) · V ; f32 I/O, bf16 MFMA.
// v6: S^T = K·Q^T. BQ=128: each wave owns 32 q (two 16-q streams) -> every
// K-frag / V-frag LDS read feeds 2 MFMAs, and each wave has 2 independent
// QK->exp->PV chains (ILP). V: coalesced global loads (R4 mapping) + swizzled
// Vt layout slot=(chunk + vcol/4)&15 on 136B rows -> conflict-free writes,
// <=2-way reads. K rows 144B skewed. BK=64, double-buffered, 1 barrier/iter.
// ---------------------------------------------------------------------------

typedef __attribute__((ext_vector_type(8))) short short8;
typedef __attribute__((ext_vector_type(4))) short short4v;
typedef __attribute__((ext_vector_type(4))) float f32x4;
typedef __attribute__((ext_vector_type(4))) unsigned int uint4v;
typedef __attribute__((ext_vector_type(2))) unsigned int uint2v;

#define DEV __device__ __forceinline__

constexpr int N_B   = 16;
constexpr int S_Q   = 4096;
constexpr int S_KV  = 4096;
constexpr int DH    = 64;
constexpr int BQ    = 128;         // q rows per block (4 waves x 32)
constexpr int BK    = 64;
constexpr int ITERS = S_KV / BK;   // 64
constexpr int KSTR  = 72;          // shorts/row: 144B (skew 4 dwords)
constexpr int VSTR  = 68;          // shorts/row: 136B (16 slots + 4 pad)

#define LOG2E 1.44269504088896340736f

DEV unsigned short f2bf(float f) {           // RNE f32 -> bf16
  union { float f; unsigned int i; } x; x.f = f;
  unsigned int r = x.i + 0x7FFFu + ((x.i >> 16) & 1u);
  return (unsigned short)(r >> 16);
}

#if __has_builtin(__builtin_amdgcn_cvt_pk_bf16_f32)
typedef __attribute__((ext_vector_type(2))) __bf16 bf16x2v;
DEV unsigned int packrne(float a, float b) {   // bf16(a) lo | bf16(b) hi, RNE
  union { bf16x2v v; unsigned int u; } x;
  x.v = __builtin_amdgcn_cvt_pk_bf16_f32(a, b);
  return x.u;
}
#else
DEV unsigned int packrne(float a, float b) {
  union { float f; unsigned int u; } ua, ub; ua.f = a; ub.f = b;
  unsigned int ra = ua.u + 0x7FFFu + ((ua.u >> 16) & 1u);
  unsigned int rb = ub.u + 0x7FFFu + ((ub.u >> 16) & 1u);
  return __builtin_amdgcn_perm(rb, ra, 0x07060302u);
}
#endif

DEV f32x4 mfma16(short4v a, short4v b, f32x4 c) {
#if __has_builtin(__builtin_amdgcn_mfma_f32_16x16x16bf16_1k)
  return __builtin_amdgcn_mfma_f32_16x16x16bf16_1k(a, b, c, 0, 0, 0);
#elif __has_builtin(__builtin_amdgcn_mfma_f32_16x16x16_bf16)
  return __builtin_amdgcn_mfma_f32_16x16x16_bf16(a, b, c, 0, 0, 0);
#else
  asm volatile("v_mfma_f32_16x16x16_bf16 %0, %1, %2, %0\n\ts_nop 7\n\ts_nop 7"
               : "+v"(c) : "v"(a), "v"(b));
  return c;
#endif
}

// stage K tile: thread t owns 16B chunks (r=t>>3, c=t&7) and (r+32, c).
DEV void stageK(unsigned short* buf, const f32x4* kA, int t) {
  const int r0 = t >> 3, c = t & 7;
  uint4v d0, d1;
  d0[0] = packrne(kA[0][0], kA[0][1]); d0[1] = packrne(kA[0][2], kA[0][3]);
  d0[2] = packrne(kA[1][0], kA[1][1]); d0[3] = packrne(kA[1][2], kA[1][3]);
  d1[0] = packrne(kA[2][0], kA[2][1]); d1[1] = packrne(kA[2][2], kA[2][3]);
  d1[2] = packrne(kA[3][0], kA[3][1]); d1[3] = packrne(kA[3][2], kA[3][3]);
  *(uint4v*)&buf[r0 * KSTR + c * 8]        = d0;
  *(uint4v*)&buf[(r0 + 32) * KSTR + c * 8] = d1;
}

// stage V^T: thread t loaded L[i] = V[kv=4*(t>>4)+i][4*(t&15)..+3] (coalesced:
// per phase 16 lanes cover one 256B row segment). Write chunk a=t>>4 of
// vcol=4x+j (x=t&15) at slot (a+x)&15: banks = 10x+const mod 32 -> 16
// distinct per phase, conflict-free.
DEV void stageV(unsigned short* buf, const f32x4* L, int t) {
  const int a = t >> 4;           // kv-chunk
  const int x = t & 15;           // vcol>>2
  const int slot = (a + x) & 15;
#pragma unroll
  for (int j = 0; j < 4; ++j) {
    uint2v d;
    d[0] = packrne(L[0][j], L[1][j]);
    d[1] = packrne(L[2][j], L[3][j]);
    *(uint2v*)&buf[(x * 4 + j) * VSTR + slot * 4] = d;
  }
}

__global__ __launch_bounds__(256, 2)
void sdpa_fwd(const float* __restrict__ Qg,
              const float* __restrict__ Kg,
              const float* __restrict__ Vg,
              const float* __restrict__ Mg,
              float* __restrict__ Og)
{
  __shared__ __align__(16) unsigned short ldsK[2][BK * KSTR];  // 2 x 9216 B
  __shared__ __align__(16) unsigned short ldsV[2][DH * VSTR];  // 2 x 8704 B

  const int n    = blockIdx.y;
  const int q0   = blockIdx.x * BQ;
  const int t    = threadIdx.x;
  const int w    = t >> 6;         // wave: owns q rows q0+32w .. +31
  const int lane = t & 63;
  const int l15  = lane & 15;
  const int quad = lane >> 4;

  // ---- Q B-frags for two 16-q streams: qA (q=q0+32w+l15), qB (+16)
  short8 qfA0, qfA1, qfB0, qfB1;
  {
    const float* qp =
        Qg + ((size_t)n * S_Q + (size_t)(q0 + w * 32 + l15)) * DH + quad * 8;
#pragma unroll
    for (int j = 0; j < 8; ++j) {
      qfA0[j] = (short)f2bf(qp[j]);
      qfA1[j] = (short)f2bf(qp[32 + j]);
      qfB0[j] = (short)f2bf(qp[16 * DH + j]);
      qfB1[j] = (short)f2bf(qp[16 * DH + 32 + j]);
    }
  }

  // ---- staging source pointers (both coalesced per 16-lane phase)
  const float* kgp = Kg + ((size_t)n * S_KV + (t >> 3)) * DH + (t & 7) * 8;
  const float* vgp =
      Vg + ((size_t)n * S_KV + (size_t)(t >> 4) * 4) * DH + (t & 15) * 4;
  const float* mrowA = Mg + (size_t)(q0 + w * 32 + l15) * S_KV + quad * 4;
  const float* mrowB = mrowA + (size_t)16 * S_KV;

  // ---- O^T accumulators per stream (C-layout: row v=16nt+quad*4+r, col q)
  f32x4 accA[4], accB[4];
#pragma unroll
  for (int nt = 0; nt < 4; ++nt)
#pragma unroll
    for (int r = 0; r < 4; ++r) { accA[nt][r] = 0.0f; accB[nt][r] = 0.0f; }
  float lrunA = 0.0f, lrunB = 0.0f;

  // ---- prologue: load + stage tile 0
  f32x4 kA[4], vL[4];
  kA[0] = *(const f32x4*)(kgp);
  kA[1] = *(const f32x4*)(kgp + 4);
  kA[2] = *(const f32x4*)(kgp + 32 * DH);
  kA[3] = *(const f32x4*)(kgp + 32 * DH + 4);
#pragma unroll
  for (int i = 0; i < 4; ++i) vL[i] = *(const f32x4*)(vgp + i * DH);
  stageK(&ldsK[0][0], kA, t);
  stageV(&ldsV[0][0], vL, t);
  __syncthreads();

  for (int it = 0; it < ITERS; ++it) {
    const int p   = it & 1;
    const int kv0 = it * BK;
    const bool more = (it + 1 < ITERS);

    // prefetch next tile into regs
    if (more) {
      const float* kn = kgp + (size_t)(kv0 + BK) * DH;
      kA[0] = *(const f32x4*)(kn);
      kA[1] = *(const f32x4*)(kn + 4);
      kA[2] = *(const f32x4*)(kn + 32 * DH);
      kA[3] = *(const f32x4*)(kn + 32 * DH + 4);
      const float* vn = vgp + (size_t)(kv0 + BK) * DH;
#pragma unroll
      for (int i = 0; i < 4; ++i) vL[i] = *(const f32x4*)(vn + i * DH);
    }

    // mask tiles for both q-streams
    f32x4 mkA[4], mkB[4];
#pragma unroll
    for (int h = 0; h < 4; ++h) {
      mkA[h] = *(const f32x4*)(mrowA + kv0 + 16 * h);
      mkB[h] = *(const f32x4*)(mrowB + kv0 + 16 * h);
    }

    // K A-frags (shared by both streams): A[m=kv=l15+16h][k=d=quad*8+j+32kk]
    short8 kf[4][2];
#pragma unroll
    for (int h = 0; h < 4; ++h)
#pragma unroll
      for (int kk = 0; kk < 2; ++kk)
        kf[h][kk] =
            *(const short8*)&ldsK[p][(l15 + 16 * h) * KSTR + (quad + 4 * kk) * 8];

    // S^T = K·Q^T for both streams; p = exp2((s/8 + m)·log2e)
    float pvA[4][4], pvB[4][4];
    float rsA = 0.0f, rsB = 0.0f;
#pragma unroll
    for (int h = 0; h < 4; ++h) {
      f32x4 cA = {0.f, 0.f, 0.f, 0.f}, cB = {0.f, 0.f, 0.f, 0.f};
      cA = __builtin_amdgcn_mfma_f32_16x16x32_bf16(kf[h][0], qfA0, cA, 0, 0, 0);
      cB = __builtin_amdgcn_mfma_f32_16x16x32_bf16(kf[h][0], qfB0, cB, 0, 0, 0);
      cA = __builtin_amdgcn_mfma_f32_16x16x32_bf16(kf[h][1], qfA1, cA, 0, 0, 0);
      cB = __builtin_amdgcn_mfma_f32_16x16x32_bf16(kf[h][1], qfB1, cB, 0, 0, 0);
#pragma unroll
      for (int r = 0; r < 4; ++r) {
        float eA = __builtin_amdgcn_exp2f(fmaf(cA[r], 0.125f, mkA[h][r]) * LOG2E);
        float eB = __builtin_amdgcn_exp2f(fmaf(cB[r], 0.125f, mkB[h][r]) * LOG2E);
        pvA[h][r] = eA; rsA += eA;
        pvB[h][r] = eB; rsB += eB;
      }
    }
    rsA += __shfl_xor(rsA, 16, 64);
    rsA += __shfl_xor(rsA, 32, 64);
    rsB += __shfl_xor(rsB, 16, 64);
    rsB += __shfl_xor(rsB, 32, 64);
    lrunA += rsA;
    lrunB += rsB;

    // P^T frags (k=kv=quad*4+j, n=q=l15) — already in-thread
    short4v pfA[4], pfB[4];
#pragma unroll
    for (int h = 0; h < 4; ++h) {
      union { uint2v u; short4v s; } ua, ub;
      ua.u[0] = packrne(pvA[h][0], pvA[h][1]);
      ua.u[1] = packrne(pvA[h][2], pvA[h][3]);
      ub.u[0] = packrne(pvB[h][0], pvB[h][1]);
      ub.u[1] = packrne(pvB[h][2], pvB[h][3]);
      pfA[h] = ua.s; pfB[h] = ub.s;
    }

    // PV: O^T += V^T·P^T ; each vf read feeds both streams.
    // vf = V^T[vcol=l15+16nt][kv chunk c=4h+quad] at slot (c + vcol/4)&15
#pragma unroll
    for (int nt = 0; nt < 4; ++nt) {
      const int vcol = l15 + 16 * nt;
      const int xr   = (l15 >> 2) + 4 * nt;
#pragma unroll
      for (int h = 0; h < 4; ++h) {
        const int slot = ((4 * h + quad) + xr) & 15;
        short4v vf = *(const short4v*)&ldsV[p][vcol * VSTR + slot * 4];
        accA[nt] = mfma16(vf, pfA[h], accA[nt]);
        accB[nt] = mfma16(vf, pfB[h], accB[nt]);
      }
    }

    // stage prefetched tile into the other buffer
    if (more) {
      stageK(&ldsK[p ^ 1][0], kA, t);
      stageV(&ldsV[p ^ 1][0], vL, t);
    }
    __syncthreads();
  }

  // ---- epilogue: O[q][v] = O^T[v][q] / l ; coalesced f32x4 stores
  const float invA = 1.0f / lrunA;
  const float invB = 1.0f / lrunB;
  float* obA = Og + ((size_t)n * S_Q + (size_t)(q0 + w * 32 + l15)) * DH
             + quad * 4;
  float* obB = obA + (size_t)16 * DH;
#pragma unroll
  for (int nt = 0; nt < 4; ++nt) {
    f32x4 oA, oB;
#pragma unroll
    for (int r = 0; r < 4; ++r) {
      oA[r] = accA[nt][r] * invA;
      oB[r] = accB[nt][r] * invB;
    }
    *(f32x4*)(obA + 16 * nt) = oA;
    *(f32x4*)(obB + 16 * nt) = oB;
  }
}

extern "C" void kernel_launch(void* const* d_in, const int* in_sizes, int n_in,
                              void* d_out, int out_size, void* d_ws, size_t ws_size,
                              hipStream_t stream) {
  (void)in_sizes; (void)n_in; (void)d_ws; (void)ws_size; (void)out_size;
  const float* q = (const float*)d_in[0];
  const float* k = (const float*)d_in[1];
  const float* v = (const float*)d_in[2];
  const float* m = (const float*)d_in[3];
  float* o = (float*)d_out;

  dim3 grid(S_Q / BQ, N_B);   // (32, 16) = 512 blocks, 2 blocks/CU
  dim3 block(256);
  hipLaunchKernelGGL(sdpa_fwd, grid, block, 0, stream, q, k, v, m, o);
}